// Round 17
// baseline (464.084 us; speedup 1.0000x reference)
//
#include <hip/hip_runtime.h>

#define B_TOTAL 131072
#define PD 200
#define KAPPA 0.8f
#define LAMDA 0.9999f
#define YITA 0.5f
#define MS_KS 216   // M LDS k-stride (27 16B slots, odd -> minimal-conflict A reads)
#define HB_RS 72    // hebb LDS row-stride (9 slots, odd)

typedef short short8 __attribute__((ext_vector_type(8)));
typedef short short4v __attribute__((ext_vector_type(4)));
typedef float f32x16 __attribute__((ext_vector_type(16)));
typedef unsigned uint4v __attribute__((ext_vector_type(4)));

static __device__ __forceinline__ float bf2f(unsigned short h) {
  union { unsigned u; float f; } v; v.u = ((unsigned)h) << 16; return v.f;
}
static __device__ __forceinline__ unsigned short f2bf(float f) {
  union { float f; unsigned u; } v; v.f = f;
  unsigned r = v.u + 0x7FFFu + ((v.u >> 16) & 1u);
  return (unsigned short)(r >> 16);
}
static __device__ __forceinline__ float fp_nl(float v) {  // clip(leaky_relu(v),-1,1)
  float t = fmaxf(v, 0.01f * v);
  return fminf(1.f, fmaxf(-1.f, t));
}
static __device__ __forceinline__ unsigned pkbf(float lo, float hi) {
  unsigned r;
  asm("v_cvt_pk_bf16_f32 %0, %1, %2" : "=v"(r) : "v"(lo), "v"(hi));
  return r;
}
// verified R2-R16: swaps 32-lane halves between a,b
static __device__ __forceinline__ void swap32(unsigned &a, unsigned &b) {
  asm("s_nop 1\n\tv_permlane32_swap_b32 %0, %1" : "+v"(a), "+v"(b));
}
static __device__ __forceinline__ uint4v mk4(unsigned a, unsigned b, unsigned c, unsigned d) {
  uint4v v; v[0] = a; v[1] = b; v[2] = c; v[3] = d; return v;
}
static __device__ __forceinline__ short8 u4s8(uint4v w) {
  union { uint4v u; short8 s; } x; x.u = w; return x.s;
}

// ---- d/s workspace layout (u16 units), DENSE 256B-aligned writes (R15-proven):
//   f in [0,192):   ((f>>6)*B + r)*64 + (f&63)
//   f in [192,200): 3*B*64 + r*8 + (f-192)
static __device__ __forceinline__ short4v ld4ds(const unsigned short* p, int r, int f0) {
  const size_t off = (f0 < 192)
      ? ((size_t)(f0 >> 6) * B_TOTAL + (size_t)r) * 64 + (f0 & 63)
      : (size_t)3 * B_TOTAL * 64 + (size_t)r * 8 + (f0 - 192);
  return *(const short4v*)(p + off);
}

__global__ void tem_init_m(const float* __restrict__ Min, float* __restrict__ oM) {
  int i = blockIdx.x * 256 + threadIdx.x;
  if (i < PD * PD) oM[i] = LAMDA * Min[i];
}

// ---- tem_main R17: R16 body wrapped in a 2-chunk loop; 256 blocks stage Ms
// ONCE per CU (was 512 blocks = 2 dispatch waves, each restaging Ms).
#define LDMS(nt, kc) (*(const short8*)(Ms + (((nt) * 32 + cl) * MS_KS + (kc) * 16 + hi * 8)))
#define MFMA_AG(ACC, A, B) asm("v_mfma_f32_32x32x16_bf16 %0, %1, %2, %0" : "+a"(ACC) : "v"(A), "v"(B))

#define STEP(PF, KC) do { \
  const short8 _b = u4s8(PF); \
  { const short8 _a = LDMS(0, KC); MFMA_AG(acc0, _a, _b); } \
  { const short8 _a = LDMS(1, KC); MFMA_AG(acc1, _a, _b); } \
  { const short8 _a = LDMS(2, KC); MFMA_AG(acc2, _a, _b); } \
  { const short8 _a = LDMS(3, KC); MFMA_AG(acc3, _a, _b); } \
  { const short8 _a = LDMS(4, KC); MFMA_AG(acc4, _a, _b); } \
  { const short8 _a = LDMS(5, KC); MFMA_AG(acc5, _a, _b); } \
  { const short8 _a = LDMS(6, KC); MFMA_AG(acc6, _a, _b); } \
  __builtin_amdgcn_sched_barrier(0); \
} while (0)

#define REPACK_LO(ACC, PF) do { \
  unsigned P0 = pkbf(fp_nl(ACC[0]), fp_nl(ACC[1])); \
  unsigned P1 = pkbf(fp_nl(ACC[2]), fp_nl(ACC[3])); \
  unsigned P2 = pkbf(fp_nl(ACC[4]), fp_nl(ACC[5])); \
  unsigned P3 = pkbf(fp_nl(ACC[6]), fp_nl(ACC[7])); \
  swap32(P0, P2); swap32(P1, P3); \
  PF = mk4(P0, P1, P2, P3); \
} while (0)
#define REPACK_HI(ACC, PF) do { \
  unsigned P4 = pkbf(fp_nl(ACC[8]),  fp_nl(ACC[9])); \
  unsigned P5 = pkbf(fp_nl(ACC[10]), fp_nl(ACC[11])); \
  unsigned P6 = pkbf(fp_nl(ACC[12]), fp_nl(ACC[13])); \
  unsigned P7 = pkbf(fp_nl(ACC[14]), fp_nl(ACC[15])); \
  swap32(P4, P6); swap32(P5, P7); \
  PF = mk4(P4, P5, P6, P7); \
} while (0)

#define ITER5 do { \
  f32x16 acc0 = {}, acc1 = {}, acc2 = {}, acc3 = {}, acc4 = {}, acc5 = {}, acc6 = {}; \
  STEP(pfA0, 0);  STEP(pfA1, 1);  STEP(pfA2, 2);  STEP(pfA3, 3); \
  STEP(pfA4, 4);  STEP(pfA5, 5);  STEP(pfA6, 6);  STEP(pfA7, 7); \
  STEP(pfA8, 8);  STEP(pfA9, 9);  STEP(pfA10, 10); STEP(pfA11, 11); \
  STEP(pfA12, 12); \
  REPACK_LO(acc0, pfA0);  REPACK_HI(acc0, pfA1); \
  REPACK_LO(acc1, pfA2);  REPACK_HI(acc1, pfA3); \
  REPACK_LO(acc2, pfA4);  REPACK_HI(acc2, pfA5); \
  REPACK_LO(acc3, pfA6);  REPACK_HI(acc3, pfA7); \
  REPACK_LO(acc4, pfA8);  REPACK_HI(acc4, pfA9); \
  REPACK_LO(acc5, pfA10); REPACK_HI(acc5, pfA11); \
  REPACK_LO(acc6, pfA12); \
} while (0)

#define FORR_LO(M_) M_(pfA0,0) M_(pfA1,16) M_(pfA2,32) M_(pfA3,48) M_(pfA4,64) M_(pfA5,80) \
                    M_(pfA6,96) M_(pfA7,112) M_(pfA8,128) M_(pfA9,144) M_(pfA10,160) M_(pfA11,176) M_(pfA12,192)
#define FORR_HI(M_) M_(pfA0,8) M_(pfA1,24) M_(pfA2,40) M_(pfA3,56) M_(pfA4,72) M_(pfA5,88) \
                    M_(pfA6,104) M_(pfA7,120) M_(pfA8,136) M_(pfA9,152) M_(pfA10,168) M_(pfA11,184)

#define INX(PF, BB) PF = mk4( \
  pkbf(xcv[((BB) + 0) % 10], xcv[((BB) + 1) % 10]), \
  pkbf(xcv[((BB) + 2) % 10], xcv[((BB) + 3) % 10]), \
  pkbf(xcv[((BB) + 4) % 10], xcv[((BB) + 5) % 10]), \
  pkbf(xcv[((BB) + 6) % 10], xcv[((BB) + 7) % 10]));
#define ING(PF, BB) PF = mk4( \
  pkbf(g2v[((BB) + 0) / 10], g2v[((BB) + 1) / 10]), \
  pkbf(g2v[((BB) + 2) / 10], g2v[((BB) + 3) / 10]), \
  pkbf(g2v[((BB) + 4) / 10], g2v[((BB) + 5) / 10]), \
  pkbf(g2v[((BB) + 6) / 10], g2v[((BB) + 7) / 10]));

#define E1W(W, F) { bins[(F) / 10] += bf2f((unsigned short)((W) & 0xFFFFu)); \
                    bins[((F) + 1) / 10] += bf2f((unsigned short)((W) >> 16)); }
#define E1PF(PF, BB) { E1W(PF[0], (BB) + 0) E1W(PF[1], (BB) + 2) E1W(PF[2], (BB) + 4) E1W(PF[3], (BB) + 6) }

#define E2AW(W, F) { ta[(F) % 10] += bf2f((unsigned short)((W) & 0xFFFFu)); \
                     ta[((F) + 1) % 10] += bf2f((unsigned short)((W) >> 16)); }
#define E2APF(PF, BB) { E2AW(PF[0], (BB) + 0) E2AW(PF[1], (BB) + 2) E2AW(PF[2], (BB) + 4) E2AW(PF[3], (BB) + 6) }

#define STG(PF, SL) (((uint4v*)StgRaw)[(wid * 4 + (SL)) * 64 + lane] = PF)

__global__ __launch_bounds__(512, 1) void tem_main(
    const float* __restrict__ xin, const float* __restrict__ gin,
    const float* __restrict__ Min, const float* __restrict__ Wc,
    const float* __restrict__ W1ie, const float* __restrict__ b1ie,
    const float* __restrict__ W2ie, const float* __restrict__ b2ie,
    const float* __restrict__ W1gg, const float* __restrict__ b1gg,
    const float* __restrict__ W2gg, const float* __restrict__ b2gg,
    const float* __restrict__ Wsp, const float* __restrict__ bsp,
    float* __restrict__ o_ginf, float* __restrict__ o_xinf,
    float* __restrict__ o_g, float* __restrict__ o_x,
    unsigned short* __restrict__ dWp, unsigned short* __restrict__ sWp) {
  // LDS: 96768 + 5120 + 20480 + 32768 = 155136 B
  __shared__ __attribute__((aligned(16))) unsigned short Ms[224 * MS_KS];
  __shared__ unsigned short xcS[256 * 10];
  __shared__ float g2S[256 * 20];
  __shared__ __attribute__((aligned(16))) char StgRaw[32768];

  unsigned* StgU = (unsigned*)StgRaw;
  float* StgF = (float*)StgRaw;

  const int tid = threadIdx.x;
  const int lane = tid & 63;
  const int wid = tid >> 6;      // 0..7
  const int cl = lane & 31;
  const int hi = lane >> 5;

  {
    unsigned* Ms32 = (unsigned*)Ms;
    for (int i = tid; i < 224 * MS_KS / 2; i += 512) Ms32[i] = 0u;
  }
  __syncthreads();
  for (int i = tid; i < 200 * 224; i += 512) {
    const int k = i / 224, n = i - k * 224;
    if (n < 200) {
      float v = Min[k * 200 + n];
      if (k == n) v += KAPPA;
      Ms[n * MS_KS + k] = f2bf(v);
    }
  }

#pragma unroll 1
  for (int chunk = 0; chunk < 2; ++chunk) {
    const int r0 = (blockIdx.x * 2 + chunk) * 256;

    __syncthreads();   // Ms ready (chunk 0) / xcS,g2S,Stg free (chunk 1)

    // prologue: t<256 g2 MLP (unrolled), t>=256 xc
    if (tid < 256) {
      const int rq = r0 + tid;
      float gv[20];
#pragma unroll
      for (int i = 0; i < 20; ++i) gv[i] = gin[(size_t)rq * 20 + i];
      float h[40];
#pragma unroll
      for (int u = 0; u < 40; ++u) h[u] = b1gg[u];
#pragma unroll
      for (int i = 0; i < 20; ++i)
#pragma unroll
        for (int u = 0; u < 40; ++u) h[u] += gv[i] * W1gg[i * 40 + u];
#pragma unroll
      for (int u = 0; u < 40; ++u) h[u] = (h[u] > 0.f) ? h[u] : (expf(h[u]) - 1.f);
#pragma unroll
      for (int o = 0; o < 20; ++o) {
        float v = b2gg[o];
#pragma unroll
        for (int u = 0; u < 40; ++u) v += h[u] * W2gg[u * 20 + o];
        g2S[tid * 20 + o] = tanhf(v);
      }
    } else {
      const int rr2 = tid - 256;
      const int rq = r0 + rr2;
      float xc[10];
#pragma unroll
      for (int o = 0; o < 10; ++o) xc[o] = 0.f;
#pragma unroll 1
      for (int j = 0; j < 45; ++j) {
        const float xv = xin[(size_t)rq * 45 + j];
#pragma unroll
        for (int o = 0; o < 10; ++o) xc[o] += xv * Wc[j * 10 + o];
      }
#pragma unroll
      for (int o = 0; o < 10; ++o) xcS[rr2 * 10 + o] = f2bf(xc[o]);
    }
    __syncthreads();

    // P1: o_g / o_x expansion, flat coalesced (fire-and-forget)
    for (int i = tid; i < 256 * 200; i += 512) {
      const int rP = i / 200, j = i - rP * 200;
      o_g[(size_t)r0 * 200 + i] = g2S[rP * 20 + j / 10];
      o_x[(size_t)r0 * 200 + i] = bf2f(xcS[rP * 10 + (j % 10)]);
    }

    const int rr = wid * 32 + cl;   // block-row this lane owns (0..255)
    const int r = r0 + rr;          // global row

    uint4v pfA0, pfA1, pfA2, pfA3, pfA4, pfA5, pfA6, pfA7, pfA8, pfA9, pfA10, pfA11, pfA12;

    // ================= ret0: x-cue =================
    {
      float xcv[10];
#pragma unroll
      for (int o = 0; o < 10; ++o) xcv[o] = bf2f(xcS[rr * 10 + o]);
      if (hi == 0) { FORR_LO(INX) }
      else         { FORR_HI(INX) pfA12 = mk4(0u, 0u, 0u, 0u); }
    }
#pragma unroll 1
    for (int it = 0; it < 5; ++it) { ITER5; }
    // E1: g_inf -> LDS stage -> flat coalesced copy
    {
      float bins[20];
#pragma unroll
      for (int t = 0; t < 20; ++t) bins[t] = 0.f;
      if (hi == 0) { FORR_LO(E1PF) } else { FORR_HI(E1PF) }
#pragma unroll
      for (int t = 0; t < 20; ++t) bins[t] += __shfl_xor(bins[t], 32);
      float h[40];
#pragma unroll
      for (int u = 0; u < 40; ++u) h[u] = b1ie[u];
#pragma unroll
      for (int gg = 0; gg < 20; ++gg) {
        const float bv = bins[gg];
#pragma unroll
        for (int u = 0; u < 40; ++u) h[u] += bv * W1ie[gg * 40 + u];
      }
#pragma unroll
      for (int u = 0; u < 40; ++u) h[u] = (h[u] > 0.f) ? h[u] : (expf(h[u]) - 1.f);
#pragma unroll
      for (int oi = 0; oi < 10; ++oi) {
        const int o = hi * 10 + oi;
        float v = b2ie[o];
#pragma unroll
        for (int u = 0; u < 40; ++u) v += h[u] * W2ie[u * 20 + o];
        StgF[rr * 20 + o] = fminf(1.f, fmaxf(-1.f, v));
      }
    }
    __syncthreads();
    for (int i = tid; i < 256 * 20; i += 512) o_ginf[(size_t)r0 * 20 + i] = StgF[i];
    __syncthreads();

    // ================= ret1: g-cue =================
    {
      float g2v[20];
#pragma unroll
      for (int o = 0; o < 20; ++o) g2v[o] = g2S[rr * 20 + o];
      if (hi == 0) { FORR_LO(ING) }
      else         { FORR_HI(ING) pfA12 = mk4(0u, 0u, 0u, 0u); }
    }
#pragma unroll 1
    for (int it = 0; it < 5; ++it) { ITER5; }
    // E2a: x_inf via LDS stage (two 128-row passes), coalesced out
    {
      float ta[10];
#pragma unroll
      for (int t = 0; t < 10; ++t) ta[t] = 0.f;
      if (hi == 0) { FORR_LO(E2APF) } else { FORR_HI(E2APF) }
#pragma unroll
      for (int t = 0; t < 10; ++t) ta[t] += __shfl_xor(ta[t], 32);
#pragma unroll 1
      for (int ph = 0; ph < 2; ++ph) {
        if ((rr >> 7) == ph) {
          const int rL = rr & 127;
          const int o0 = hi ? 23 : 0, o1 = hi ? 45 : 23;
#pragma unroll 1
          for (int o = o0; o < o1; ++o) {
            float v = bsp[o];
#pragma unroll
            for (int a = 0; a < 10; ++a) v += ta[a] * Wsp[a * 45 + o];
            StgF[rL * 45 + o] = v;
          }
        }
        __syncthreads();
        for (int i = tid; i < 128 * 45; i += 512)
          o_xinf[((size_t)r0 + ph * 128) * 45 + i] = StgF[i];
        __syncthreads();
      }
    }
    // E2b: d/s staging via rotating LDS -> DENSE f-block-major writes (R15).
    {
      unsigned int* dW32 = (unsigned int*)dWp;
      unsigned int* sW32 = (unsigned int*)sWp;
#pragma unroll 1
      for (int rnd = 0; rnd < 4; ++rnd) {
        if (rnd == 0)      { STG(pfA0, 0);  STG(pfA1, 1);  STG(pfA2, 2);   STG(pfA3, 3);  }
        else if (rnd == 1) { STG(pfA4, 0);  STG(pfA5, 1);  STG(pfA6, 2);   STG(pfA7, 3);  }
        else if (rnd == 2) { STG(pfA8, 0);  STG(pfA9, 1);  STG(pfA10, 2);  STG(pfA11, 3); }
        else               { STG(pfA12, 0); }
        asm volatile("s_waitcnt lgkmcnt(0)" ::: "memory");   // wave-sync LDS visibility
        __builtin_amdgcn_sched_barrier(0);                    // rule #18 fence
        if (rnd < 3) {
#pragma unroll 1
          for (int itw = 0; itw < 16; ++itw) {
            const int u = itw * 64 + lane;
            const int row = u >> 5, jpo = u & 31;
            const int kcl = jpo >> 3, rem = jpo & 7;
            const int hi2 = rem >> 2, jw = rem & 3;
            const unsigned word = StgU[(((wid * 4 + kcl) * 2 + hi2) * 32 + row) * 4 + jw];
            const int rB = wid * 32 + row;
            const int jp = rnd * 32 + jpo;
            const int j0 = jp * 2;
            const float p0 = bf2f((unsigned short)(word & 0xFFFFu));
            const float p1 = bf2f((unsigned short)(word >> 16));
            const float x0 = bf2f(xcS[rB * 10 + (j0 % 10)]);
            const float x1 = bf2f(xcS[rB * 10 + ((j0 + 1) % 10)]);
            const float pi0 = fp_nl(g2S[rB * 20 + (j0 / 10)] * x0);
            const float pi1 = fp_nl(g2S[rB * 20 + ((j0 + 1) / 10)] * x1);
            const unsigned dpack = (unsigned)f2bf(pi0 - p0) | ((unsigned)f2bf(pi1 - p1) << 16);
            const unsigned spack = (unsigned)f2bf(pi0 + p0) | ((unsigned)f2bf(pi1 + p1) << 16);
            const size_t oidx = ((size_t)rnd * B_TOTAL + (size_t)(r0 + rB)) * 32 + jpo;
            dW32[oidx] = dpack;
            sW32[oidx] = spack;
          }
        } else {
#pragma unroll 1
          for (int itw = 0; itw < 2; ++itw) {
            const int u = itw * 64 + lane;
            const int row = u >> 2, q = u & 3;   // jp = 96 + q
            const unsigned word = StgU[((wid * 8) * 32 + row) * 4 + q];
            const int rB = wid * 32 + row;
            const int j0 = (96 + q) * 2;
            const float p0 = bf2f((unsigned short)(word & 0xFFFFu));
            const float p1 = bf2f((unsigned short)(word >> 16));
            const float x0 = bf2f(xcS[rB * 10 + (j0 % 10)]);
            const float x1 = bf2f(xcS[rB * 10 + ((j0 + 1) % 10)]);
            const float pi0 = fp_nl(g2S[rB * 20 + (j0 / 10)] * x0);
            const float pi1 = fp_nl(g2S[rB * 20 + ((j0 + 1) / 10)] * x1);
            const unsigned dpack = (unsigned)f2bf(pi0 - p0) | ((unsigned)f2bf(pi1 - p1) << 16);
            const unsigned spack = (unsigned)f2bf(pi0 + p0) | ((unsigned)f2bf(pi1 + p1) << 16);
            const size_t oidx = (size_t)3 * B_TOTAL * 32 + (size_t)(r0 + rB) * 4 + q;
            dW32[oidx] = dpack;
            sW32[oidx] = spack;
          }
        }
        __builtin_amdgcn_sched_barrier(0);
      }
    }
  }
}

// hebb: f-block-major d/s input, LDS transpose, split-K, 256 blocks (R15).
__global__ __launch_bounds__(448, 1) void tem_hebb(
    const unsigned short* __restrict__ dWp, const unsigned short* __restrict__ sWp,
    float* __restrict__ oM) {
  __shared__ __attribute__((aligned(16))) unsigned short dT[224 * HB_RS];
  __shared__ __attribute__((aligned(16))) unsigned short sT[224 * HB_RS];
  const int tid = threadIdx.x;
  const int lane = tid & 63, wid = tid >> 6;   // 7 waves
  const int cl = lane & 31, hi = lane >> 5;
  for (int i = tid; i < 224 * HB_RS; i += 448) { dT[i] = 0; sT[i] = 0; }
  f32x16 hacc[7];
#pragma unroll
  for (int nt = 0; nt < 7; ++nt)
#pragma unroll
    for (int q = 0; q < 16; ++q) hacc[nt][q] = 0.f;
  const int kbase = blockIdx.x * 512;
#pragma unroll 1
  for (int sub = 0; sub < 8; ++sub) {
    __syncthreads();
    const int kb = kbase + sub * 64;
#pragma unroll 1
    for (int i = tid; i < 64 * 50; i += 448) {
      const int rr = i / 50, fq = i - rr * 50;
      const int f0 = fq * 4;
      const short4v d4 = ld4ds(dWp, kb + rr, f0);
      const short4v s4 = ld4ds(sWp, kb + rr, f0);
#pragma unroll
      for (int q = 0; q < 4; ++q) {
        dT[(f0 + q) * HB_RS + rr] = (unsigned short)d4[q];
        sT[(f0 + q) * HB_RS + rr] = (unsigned short)s4[q];
      }
    }
    __syncthreads();
#pragma unroll
    for (int kc = 0; kc < 4; ++kc) {
      const short8 af = *(const short8*)(dT + ((wid * 32 + cl) * HB_RS + kc * 16 + hi * 8));
#pragma unroll
      for (int nt = 0; nt < 7; ++nt) {
        const short8 bfr = *(const short8*)(sT + ((nt * 32 + cl) * HB_RS + kc * 16 + hi * 8));
        hacc[nt] = __builtin_amdgcn_mfma_f32_32x32x16_bf16(af, bfr, hacc[nt], 0, 0, 0);
      }
    }
  }
  const float scale = YITA / (float)B_TOTAL;
#pragma unroll
  for (int nt = 0; nt < 7; ++nt) {
    const int j = nt * 32 + cl;
    if (j < 200) {
#pragma unroll
      for (int rg = 0; rg < 16; ++rg) {
        const int ii = wid * 32 + (rg & 3) + 8 * (rg >> 2) + 4 * hi;
        if (ii < 200) atomicAdd(&oM[ii * 200 + j], hacc[nt][rg] * scale);
      }
    }
  }
}

extern "C" void kernel_launch(void* const* d_in, const int* in_sizes, int n_in,
                              void* d_out, int out_size, void* d_ws, size_t ws_size,
                              hipStream_t stream) {
  (void)in_sizes; (void)n_in; (void)out_size; (void)ws_size;
  const float* xin  = (const float*)d_in[0];
  const float* gin  = (const float*)d_in[1];
  const float* Min  = (const float*)d_in[2];
  const float* Wc   = (const float*)d_in[3];
  const float* W1ie = (const float*)d_in[4];
  const float* b1ie = (const float*)d_in[5];
  const float* W2ie = (const float*)d_in[6];
  const float* b2ie = (const float*)d_in[7];
  const float* W1gg = (const float*)d_in[8];
  const float* b1gg = (const float*)d_in[9];
  const float* W2gg = (const float*)d_in[10];
  const float* b2gg = (const float*)d_in[11];
  const float* Wsp  = (const float*)d_in[12];
  const float* bsp  = (const float*)d_in[13];

  float* out = (float*)d_out;
  float* o_ginf = out;
  float* o_xinf = out + (size_t)B_TOTAL * 20;
  float* o_g    = out + (size_t)B_TOTAL * 65;
  float* o_x    = out + (size_t)B_TOTAL * 265;
  float* o_M    = out + (size_t)B_TOTAL * 465;

  unsigned short* dWp = (unsigned short*)d_ws;
  unsigned short* sWp = dWp + (size_t)B_TOTAL * PD;

  tem_init_m<<<(PD * PD + 255) / 256, 256, 0, stream>>>(Min, o_M);
  tem_main<<<256, 512, 0, stream>>>(xin, gin, Min, Wc, W1ie, b1ie, W2ie, b2ie,
                                    W1gg, b1gg, W2gg, b2gg, Wsp, bsp,
                                    o_ginf, o_xinf, o_g, o_x, dWp, sWp);
  tem_hebb<<<256, 448, 0, stream>>>(dWp, sWp, o_M);
}

// Round 18
// 446.573 us; speedup vs baseline: 1.0392x; 1.0392x over previous
//
#include <hip/hip_runtime.h>

#define B_TOTAL 131072
#define PD 200
#define KAPPA 0.8f
#define LAMDA 0.9999f
#define YITA 0.5f
#define MS_KS 216   // M LDS k-stride (27 16B slots, odd -> minimal-conflict A reads)
#define HB_RS 72    // hebb LDS row-stride (9 slots, odd)

typedef short short8 __attribute__((ext_vector_type(8)));
typedef short short4v __attribute__((ext_vector_type(4)));
typedef float f32x16 __attribute__((ext_vector_type(16)));
typedef unsigned uint4v __attribute__((ext_vector_type(4)));

static __device__ __forceinline__ float bf2f(unsigned short h) {
  union { unsigned u; float f; } v; v.u = ((unsigned)h) << 16; return v.f;
}
static __device__ __forceinline__ unsigned short f2bf(float f) {
  union { float f; unsigned u; } v; v.f = f;
  unsigned r = v.u + 0x7FFFu + ((v.u >> 16) & 1u);
  return (unsigned short)(r >> 16);
}
static __device__ __forceinline__ float fp_nl(float v) {  // clip(leaky_relu(v),-1,1)
  float t = fmaxf(v, 0.01f * v);
  return fminf(1.f, fmaxf(-1.f, t));
}
static __device__ __forceinline__ unsigned pkbf(float lo, float hi) {
  unsigned r;
  asm("v_cvt_pk_bf16_f32 %0, %1, %2" : "=v"(r) : "v"(lo), "v"(hi));
  return r;
}
// verified R2-R17: swaps 32-lane halves between a,b
static __device__ __forceinline__ void swap32(unsigned &a, unsigned &b) {
  asm("s_nop 1\n\tv_permlane32_swap_b32 %0, %1" : "+v"(a), "+v"(b));
}
static __device__ __forceinline__ uint4v mk4(unsigned a, unsigned b, unsigned c, unsigned d) {
  uint4v v; v[0] = a; v[1] = b; v[2] = c; v[3] = d; return v;
}
static __device__ __forceinline__ short8 u4s8(uint4v w) {
  union { uint4v u; short8 s; } x; x.u = w; return x.s;
}

// ---- d/s workspace layout (u16 units), DENSE 256B-aligned writes (R15-proven):
//   f in [0,192):   ((f>>6)*B + r)*64 + (f&63)
//   f in [192,200): 3*B*64 + r*8 + (f-192)
static __device__ __forceinline__ short4v ld4ds(const unsigned short* p, int r, int f0) {
  const size_t off = (f0 < 192)
      ? ((size_t)(f0 >> 6) * B_TOTAL + (size_t)r) * 64 + (f0 & 63)
      : (size_t)3 * B_TOTAL * 64 + (size_t)r * 8 + (f0 - 192);
  return *(const short4v*)(p + off);
}

__global__ void tem_init_m(const float* __restrict__ Min, float* __restrict__ oM) {
  int i = blockIdx.x * 256 + threadIdx.x;
  if (i < PD * PD) oM[i] = LAMDA * Min[i];
}

// ---- tem_main (R16 final): 512 thr = 2 waves/SIMD; acc in AGPR ("+a" asm),
// pf in 13 named VGPR quads; sequential retrievals; P1 output expansion
// folded in (fire-and-forget); staged E1/E2a outputs; dense f-block E2b.
#define LDMS(nt, kc) (*(const short8*)(Ms + (((nt) * 32 + cl) * MS_KS + (kc) * 16 + hi * 8)))
#define MFMA_AG(ACC, A, B) asm("v_mfma_f32_32x32x16_bf16 %0, %1, %2, %0" : "+a"(ACC) : "v"(A), "v"(B))

#define STEP(PF, KC) do { \
  const short8 _b = u4s8(PF); \
  { const short8 _a = LDMS(0, KC); MFMA_AG(acc0, _a, _b); } \
  { const short8 _a = LDMS(1, KC); MFMA_AG(acc1, _a, _b); } \
  { const short8 _a = LDMS(2, KC); MFMA_AG(acc2, _a, _b); } \
  { const short8 _a = LDMS(3, KC); MFMA_AG(acc3, _a, _b); } \
  { const short8 _a = LDMS(4, KC); MFMA_AG(acc4, _a, _b); } \
  { const short8 _a = LDMS(5, KC); MFMA_AG(acc5, _a, _b); } \
  { const short8 _a = LDMS(6, KC); MFMA_AG(acc6, _a, _b); } \
  __builtin_amdgcn_sched_barrier(0); \
} while (0)

#define REPACK_LO(ACC, PF) do { \
  unsigned P0 = pkbf(fp_nl(ACC[0]), fp_nl(ACC[1])); \
  unsigned P1 = pkbf(fp_nl(ACC[2]), fp_nl(ACC[3])); \
  unsigned P2 = pkbf(fp_nl(ACC[4]), fp_nl(ACC[5])); \
  unsigned P3 = pkbf(fp_nl(ACC[6]), fp_nl(ACC[7])); \
  swap32(P0, P2); swap32(P1, P3); \
  PF = mk4(P0, P1, P2, P3); \
} while (0)
#define REPACK_HI(ACC, PF) do { \
  unsigned P4 = pkbf(fp_nl(ACC[8]),  fp_nl(ACC[9])); \
  unsigned P5 = pkbf(fp_nl(ACC[10]), fp_nl(ACC[11])); \
  unsigned P6 = pkbf(fp_nl(ACC[12]), fp_nl(ACC[13])); \
  unsigned P7 = pkbf(fp_nl(ACC[14]), fp_nl(ACC[15])); \
  swap32(P4, P6); swap32(P5, P7); \
  PF = mk4(P4, P5, P6, P7); \
} while (0)

#define ITER5 do { \
  f32x16 acc0 = {}, acc1 = {}, acc2 = {}, acc3 = {}, acc4 = {}, acc5 = {}, acc6 = {}; \
  STEP(pfA0, 0);  STEP(pfA1, 1);  STEP(pfA2, 2);  STEP(pfA3, 3); \
  STEP(pfA4, 4);  STEP(pfA5, 5);  STEP(pfA6, 6);  STEP(pfA7, 7); \
  STEP(pfA8, 8);  STEP(pfA9, 9);  STEP(pfA10, 10); STEP(pfA11, 11); \
  STEP(pfA12, 12); \
  REPACK_LO(acc0, pfA0);  REPACK_HI(acc0, pfA1); \
  REPACK_LO(acc1, pfA2);  REPACK_HI(acc1, pfA3); \
  REPACK_LO(acc2, pfA4);  REPACK_HI(acc2, pfA5); \
  REPACK_LO(acc3, pfA6);  REPACK_HI(acc3, pfA7); \
  REPACK_LO(acc4, pfA8);  REPACK_HI(acc4, pfA9); \
  REPACK_LO(acc5, pfA10); REPACK_HI(acc5, pfA11); \
  REPACK_LO(acc6, pfA12); \
} while (0)

#define FORR_LO(M_) M_(pfA0,0) M_(pfA1,16) M_(pfA2,32) M_(pfA3,48) M_(pfA4,64) M_(pfA5,80) \
                    M_(pfA6,96) M_(pfA7,112) M_(pfA8,128) M_(pfA9,144) M_(pfA10,160) M_(pfA11,176) M_(pfA12,192)
#define FORR_HI(M_) M_(pfA0,8) M_(pfA1,24) M_(pfA2,40) M_(pfA3,56) M_(pfA4,72) M_(pfA5,88) \
                    M_(pfA6,104) M_(pfA7,120) M_(pfA8,136) M_(pfA9,152) M_(pfA10,168) M_(pfA11,184)

#define INX(PF, BB) PF = mk4( \
  pkbf(xcv[((BB) + 0) % 10], xcv[((BB) + 1) % 10]), \
  pkbf(xcv[((BB) + 2) % 10], xcv[((BB) + 3) % 10]), \
  pkbf(xcv[((BB) + 4) % 10], xcv[((BB) + 5) % 10]), \
  pkbf(xcv[((BB) + 6) % 10], xcv[((BB) + 7) % 10]));
#define ING(PF, BB) PF = mk4( \
  pkbf(g2v[((BB) + 0) / 10], g2v[((BB) + 1) / 10]), \
  pkbf(g2v[((BB) + 2) / 10], g2v[((BB) + 3) / 10]), \
  pkbf(g2v[((BB) + 4) / 10], g2v[((BB) + 5) / 10]), \
  pkbf(g2v[((BB) + 6) / 10], g2v[((BB) + 7) / 10]));

#define E1W(W, F) { bins[(F) / 10] += bf2f((unsigned short)((W) & 0xFFFFu)); \
                    bins[((F) + 1) / 10] += bf2f((unsigned short)((W) >> 16)); }
#define E1PF(PF, BB) { E1W(PF[0], (BB) + 0) E1W(PF[1], (BB) + 2) E1W(PF[2], (BB) + 4) E1W(PF[3], (BB) + 6) }

#define E2AW(W, F) { ta[(F) % 10] += bf2f((unsigned short)((W) & 0xFFFFu)); \
                     ta[((F) + 1) % 10] += bf2f((unsigned short)((W) >> 16)); }
#define E2APF(PF, BB) { E2AW(PF[0], (BB) + 0) E2AW(PF[1], (BB) + 2) E2AW(PF[2], (BB) + 4) E2AW(PF[3], (BB) + 6) }

#define STG(PF, SL) (((uint4v*)StgRaw)[(wid * 4 + (SL)) * 64 + lane] = PF)

__global__ __launch_bounds__(512, 1) void tem_main(
    const float* __restrict__ xin, const float* __restrict__ gin,
    const float* __restrict__ Min, const float* __restrict__ Wc,
    const float* __restrict__ W1ie, const float* __restrict__ b1ie,
    const float* __restrict__ W2ie, const float* __restrict__ b2ie,
    const float* __restrict__ W1gg, const float* __restrict__ b1gg,
    const float* __restrict__ W2gg, const float* __restrict__ b2gg,
    const float* __restrict__ Wsp, const float* __restrict__ bsp,
    float* __restrict__ o_ginf, float* __restrict__ o_xinf,
    float* __restrict__ o_g, float* __restrict__ o_x,
    unsigned short* __restrict__ dWp, unsigned short* __restrict__ sWp) {
  // LDS: 96768 + 5120 + 20480 + 32768 = 155136 B
  __shared__ __attribute__((aligned(16))) unsigned short Ms[224 * MS_KS];
  __shared__ unsigned short xcS[256 * 10];
  __shared__ float g2S[256 * 20];
  __shared__ __attribute__((aligned(16))) char StgRaw[32768];

  unsigned* StgU = (unsigned*)StgRaw;
  float* StgF = (float*)StgRaw;

  const int tid = threadIdx.x;
  const int lane = tid & 63;
  const int wid = tid >> 6;      // 0..7
  const int cl = lane & 31;
  const int hi = lane >> 5;
  const int r0 = blockIdx.x * 256;

  {
    unsigned* Ms32 = (unsigned*)Ms;
    for (int i = tid; i < 224 * MS_KS / 2; i += 512) Ms32[i] = 0u;
  }
  __syncthreads();
  for (int i = tid; i < 200 * 224; i += 512) {
    const int k = i / 224, n = i - k * 224;
    if (n < 200) {
      float v = Min[k * 200 + n];
      if (k == n) v += KAPPA;
      Ms[n * MS_KS + k] = f2bf(v);
    }
  }

  // prologue: t<256 g2 MLP (unrolled), t>=256 xc
  if (tid < 256) {
    const int rq = r0 + tid;
    float gv[20];
#pragma unroll
    for (int i = 0; i < 20; ++i) gv[i] = gin[(size_t)rq * 20 + i];
    float h[40];
#pragma unroll
    for (int u = 0; u < 40; ++u) h[u] = b1gg[u];
#pragma unroll
    for (int i = 0; i < 20; ++i)
#pragma unroll
      for (int u = 0; u < 40; ++u) h[u] += gv[i] * W1gg[i * 40 + u];
#pragma unroll
    for (int u = 0; u < 40; ++u) h[u] = (h[u] > 0.f) ? h[u] : (expf(h[u]) - 1.f);
#pragma unroll
    for (int o = 0; o < 20; ++o) {
      float v = b2gg[o];
#pragma unroll
      for (int u = 0; u < 40; ++u) v += h[u] * W2gg[u * 20 + o];
      g2S[tid * 20 + o] = tanhf(v);
    }
  } else {
    const int rr2 = tid - 256;
    const int rq = r0 + rr2;
    float xc[10];
#pragma unroll
    for (int o = 0; o < 10; ++o) xc[o] = 0.f;
#pragma unroll 1
    for (int j = 0; j < 45; ++j) {
      const float xv = xin[(size_t)rq * 45 + j];
#pragma unroll
      for (int o = 0; o < 10; ++o) xc[o] += xv * Wc[j * 10 + o];
    }
#pragma unroll
    for (int o = 0; o < 10; ++o) xcS[rr2 * 10 + o] = f2bf(xc[o]);
  }
  __syncthreads();

  // P1: o_g / o_x expansion, flat coalesced (fire-and-forget; drains under
  // the retrieval compute below)
  for (int i = tid; i < 256 * 200; i += 512) {
    const int rP = i / 200, j = i - rP * 200;
    o_g[(size_t)r0 * 200 + i] = g2S[rP * 20 + j / 10];
    o_x[(size_t)r0 * 200 + i] = bf2f(xcS[rP * 10 + (j % 10)]);
  }

  const int rr = wid * 32 + cl;   // block-row this lane owns (0..255)
  const int r = r0 + rr;          // global row

  uint4v pfA0, pfA1, pfA2, pfA3, pfA4, pfA5, pfA6, pfA7, pfA8, pfA9, pfA10, pfA11, pfA12;

  // ================= ret0: x-cue =================
  {
    float xcv[10];
#pragma unroll
    for (int o = 0; o < 10; ++o) xcv[o] = bf2f(xcS[rr * 10 + o]);
    if (hi == 0) { FORR_LO(INX) }
    else         { FORR_HI(INX) pfA12 = mk4(0u, 0u, 0u, 0u); }
  }
#pragma unroll 1
  for (int it = 0; it < 5; ++it) { ITER5; }
  // E1: g_inf -> LDS stage -> flat coalesced copy
  {
    float bins[20];
#pragma unroll
    for (int t = 0; t < 20; ++t) bins[t] = 0.f;
    if (hi == 0) { FORR_LO(E1PF) } else { FORR_HI(E1PF) }
#pragma unroll
    for (int t = 0; t < 20; ++t) bins[t] += __shfl_xor(bins[t], 32);
    float h[40];
#pragma unroll
    for (int u = 0; u < 40; ++u) h[u] = b1ie[u];
#pragma unroll
    for (int gg = 0; gg < 20; ++gg) {
      const float bv = bins[gg];
#pragma unroll
      for (int u = 0; u < 40; ++u) h[u] += bv * W1ie[gg * 40 + u];
    }
#pragma unroll
    for (int u = 0; u < 40; ++u) h[u] = (h[u] > 0.f) ? h[u] : (expf(h[u]) - 1.f);
#pragma unroll
    for (int oi = 0; oi < 10; ++oi) {
      const int o = hi * 10 + oi;
      float v = b2ie[o];
#pragma unroll
      for (int u = 0; u < 40; ++u) v += h[u] * W2ie[u * 20 + o];
      StgF[rr * 20 + o] = fminf(1.f, fmaxf(-1.f, v));
    }
  }
  __syncthreads();
  for (int i = tid; i < 256 * 20; i += 512) o_ginf[(size_t)r0 * 20 + i] = StgF[i];
  __syncthreads();

  // ================= ret1: g-cue =================
  {
    float g2v[20];
#pragma unroll
    for (int o = 0; o < 20; ++o) g2v[o] = g2S[rr * 20 + o];
    if (hi == 0) { FORR_LO(ING) }
    else         { FORR_HI(ING) pfA12 = mk4(0u, 0u, 0u, 0u); }
  }
#pragma unroll 1
  for (int it = 0; it < 5; ++it) { ITER5; }
  // E2a: x_inf via LDS stage (two 128-row passes), coalesced out
  {
    float ta[10];
#pragma unroll
    for (int t = 0; t < 10; ++t) ta[t] = 0.f;
    if (hi == 0) { FORR_LO(E2APF) } else { FORR_HI(E2APF) }
#pragma unroll
    for (int t = 0; t < 10; ++t) ta[t] += __shfl_xor(ta[t], 32);
#pragma unroll 1
    for (int ph = 0; ph < 2; ++ph) {
      if ((rr >> 7) == ph) {
        const int rL = rr & 127;
        const int o0 = hi ? 23 : 0, o1 = hi ? 45 : 23;
#pragma unroll 1
        for (int o = o0; o < o1; ++o) {
          float v = bsp[o];
#pragma unroll
          for (int a = 0; a < 10; ++a) v += ta[a] * Wsp[a * 45 + o];
          StgF[rL * 45 + o] = v;
        }
      }
      __syncthreads();
      for (int i = tid; i < 128 * 45; i += 512)
        o_xinf[((size_t)r0 + ph * 128) * 45 + i] = StgF[i];
      __syncthreads();
    }
  }
  // E2b: d/s staging via rotating LDS -> DENSE f-block-major writes (R15).
  {
    unsigned int* dW32 = (unsigned int*)dWp;
    unsigned int* sW32 = (unsigned int*)sWp;
#pragma unroll 1
    for (int rnd = 0; rnd < 4; ++rnd) {
      if (rnd == 0)      { STG(pfA0, 0);  STG(pfA1, 1);  STG(pfA2, 2);   STG(pfA3, 3);  }
      else if (rnd == 1) { STG(pfA4, 0);  STG(pfA5, 1);  STG(pfA6, 2);   STG(pfA7, 3);  }
      else if (rnd == 2) { STG(pfA8, 0);  STG(pfA9, 1);  STG(pfA10, 2);  STG(pfA11, 3); }
      else               { STG(pfA12, 0); }
      asm volatile("s_waitcnt lgkmcnt(0)" ::: "memory");   // wave-sync LDS visibility
      __builtin_amdgcn_sched_barrier(0);                    // rule #18 fence
      if (rnd < 3) {
#pragma unroll 1
        for (int itw = 0; itw < 16; ++itw) {
          const int u = itw * 64 + lane;
          const int row = u >> 5, jpo = u & 31;
          const int kcl = jpo >> 3, rem = jpo & 7;
          const int hi2 = rem >> 2, jw = rem & 3;
          const unsigned word = StgU[(((wid * 4 + kcl) * 2 + hi2) * 32 + row) * 4 + jw];
          const int rB = wid * 32 + row;
          const int jp = rnd * 32 + jpo;
          const int j0 = jp * 2;
          const float p0 = bf2f((unsigned short)(word & 0xFFFFu));
          const float p1 = bf2f((unsigned short)(word >> 16));
          const float x0 = bf2f(xcS[rB * 10 + (j0 % 10)]);
          const float x1 = bf2f(xcS[rB * 10 + ((j0 + 1) % 10)]);
          const float pi0 = fp_nl(g2S[rB * 20 + (j0 / 10)] * x0);
          const float pi1 = fp_nl(g2S[rB * 20 + ((j0 + 1) / 10)] * x1);
          const unsigned dpack = (unsigned)f2bf(pi0 - p0) | ((unsigned)f2bf(pi1 - p1) << 16);
          const unsigned spack = (unsigned)f2bf(pi0 + p0) | ((unsigned)f2bf(pi1 + p1) << 16);
          const size_t oidx = ((size_t)rnd * B_TOTAL + (size_t)(r0 + rB)) * 32 + jpo;
          dW32[oidx] = dpack;
          sW32[oidx] = spack;
        }
      } else {
#pragma unroll 1
        for (int itw = 0; itw < 2; ++itw) {
          const int u = itw * 64 + lane;
          const int row = u >> 2, q = u & 3;   // jp = 96 + q
          const unsigned word = StgU[((wid * 8) * 32 + row) * 4 + q];
          const int rB = wid * 32 + row;
          const int j0 = (96 + q) * 2;
          const float p0 = bf2f((unsigned short)(word & 0xFFFFu));
          const float p1 = bf2f((unsigned short)(word >> 16));
          const float x0 = bf2f(xcS[rB * 10 + (j0 % 10)]);
          const float x1 = bf2f(xcS[rB * 10 + ((j0 + 1) % 10)]);
          const float pi0 = fp_nl(g2S[rB * 20 + (j0 / 10)] * x0);
          const float pi1 = fp_nl(g2S[rB * 20 + ((j0 + 1) / 10)] * x1);
          const unsigned dpack = (unsigned)f2bf(pi0 - p0) | ((unsigned)f2bf(pi1 - p1) << 16);
          const unsigned spack = (unsigned)f2bf(pi0 + p0) | ((unsigned)f2bf(pi1 + p1) << 16);
          const size_t oidx = (size_t)3 * B_TOTAL * 32 + (size_t)(r0 + rB) * 4 + q;
          dW32[oidx] = dpack;
          sW32[oidx] = spack;
        }
      }
      __builtin_amdgcn_sched_barrier(0);
    }
  }
}

// hebb: f-block-major d/s input, LDS transpose, split-K, 256 blocks (R15).
__global__ __launch_bounds__(448, 1) void tem_hebb(
    const unsigned short* __restrict__ dWp, const unsigned short* __restrict__ sWp,
    float* __restrict__ oM) {
  __shared__ __attribute__((aligned(16))) unsigned short dT[224 * HB_RS];
  __shared__ __attribute__((aligned(16))) unsigned short sT[224 * HB_RS];
  const int tid = threadIdx.x;
  const int lane = tid & 63, wid = tid >> 6;   // 7 waves
  const int cl = lane & 31, hi = lane >> 5;
  for (int i = tid; i < 224 * HB_RS; i += 448) { dT[i] = 0; sT[i] = 0; }
  f32x16 hacc[7];
#pragma unroll
  for (int nt = 0; nt < 7; ++nt)
#pragma unroll
    for (int q = 0; q < 16; ++q) hacc[nt][q] = 0.f;
  const int kbase = blockIdx.x * 512;
#pragma unroll 1
  for (int sub = 0; sub < 8; ++sub) {
    __syncthreads();
    const int kb = kbase + sub * 64;
#pragma unroll 1
    for (int i = tid; i < 64 * 50; i += 448) {
      const int rr = i / 50, fq = i - rr * 50;
      const int f0 = fq * 4;
      const short4v d4 = ld4ds(dWp, kb + rr, f0);
      const short4v s4 = ld4ds(sWp, kb + rr, f0);
#pragma unroll
      for (int q = 0; q < 4; ++q) {
        dT[(f0 + q) * HB_RS + rr] = (unsigned short)d4[q];
        sT[(f0 + q) * HB_RS + rr] = (unsigned short)s4[q];
      }
    }
    __syncthreads();
#pragma unroll
    for (int kc = 0; kc < 4; ++kc) {
      const short8 af = *(const short8*)(dT + ((wid * 32 + cl) * HB_RS + kc * 16 + hi * 8));
#pragma unroll
      for (int nt = 0; nt < 7; ++nt) {
        const short8 bfr = *(const short8*)(sT + ((nt * 32 + cl) * HB_RS + kc * 16 + hi * 8));
        hacc[nt] = __builtin_amdgcn_mfma_f32_32x32x16_bf16(af, bfr, hacc[nt], 0, 0, 0);
      }
    }
  }
  const float scale = YITA / (float)B_TOTAL;
#pragma unroll
  for (int nt = 0; nt < 7; ++nt) {
    const int j = nt * 32 + cl;
    if (j < 200) {
#pragma unroll
      for (int rg = 0; rg < 16; ++rg) {
        const int ii = wid * 32 + (rg & 3) + 8 * (rg >> 2) + 4 * hi;
        if (ii < 200) atomicAdd(&oM[ii * 200 + j], hacc[nt][rg] * scale);
      }
    }
  }
}

extern "C" void kernel_launch(void* const* d_in, const int* in_sizes, int n_in,
                              void* d_out, int out_size, void* d_ws, size_t ws_size,
                              hipStream_t stream) {
  (void)in_sizes; (void)n_in; (void)out_size; (void)ws_size;
  const float* xin  = (const float*)d_in[0];
  const float* gin  = (const float*)d_in[1];
  const float* Min  = (const float*)d_in[2];
  const float* Wc   = (const float*)d_in[3];
  const float* W1ie = (const float*)d_in[4];
  const float* b1ie = (const float*)d_in[5];
  const float* W2ie = (const float*)d_in[6];
  const float* b2ie = (const float*)d_in[7];
  const float* W1gg = (const float*)d_in[8];
  const float* b1gg = (const float*)d_in[9];
  const float* W2gg = (const float*)d_in[10];
  const float* b2gg = (const float*)d_in[11];
  const float* Wsp  = (const float*)d_in[12];
  const float* bsp  = (const float*)d_in[13];

  float* out = (float*)d_out;
  float* o_ginf = out;
  float* o_xinf = out + (size_t)B_TOTAL * 20;
  float* o_g    = out + (size_t)B_TOTAL * 65;
  float* o_x    = out + (size_t)B_TOTAL * 265;
  float* o_M    = out + (size_t)B_TOTAL * 465;

  unsigned short* dWp = (unsigned short*)d_ws;
  unsigned short* sWp = dWp + (size_t)B_TOTAL * PD;

  tem_init_m<<<(PD * PD + 255) / 256, 256, 0, stream>>>(Min, o_M);
  tem_main<<<512, 512, 0, stream>>>(xin, gin, Min, Wc, W1ie, b1ie, W2ie, b2ie,
                                    W1gg, b1gg, W2gg, b2gg, Wsp, bsp,
                                    o_ginf, o_xinf, o_g, o_x, dWp, sWp);
  tem_hebb<<<256, 448, 0, stream>>>(dWp, sWp, o_M);
}